// Round 6
// baseline (2894.201 us; speedup 1.0000x reference)
//
#include <hip/hip_runtime.h>
#include <math.h>

#define NN 50000
#define NE 800000

// ---------------------------------------------------------------- utility
__global__ void zero_counts_kernel(int* counts) {
  int i = blockIdx.x * blockDim.x + threadIdx.x;
  if (i < NN) counts[i] = 0;
}

__global__ void count_kernel(const int* __restrict__ dst, int* __restrict__ counts) {
  int e = blockIdx.x * blockDim.x + threadIdx.x;
  if (e < NE) atomicAdd(&counts[dst[e]], 1);
}

// single block, 1024 threads: exclusive scan of counts -> rowptr/cursor,
// plus avg_log = mean(log1p(counts)) -> scal[0]
__global__ void scan_kernel(const int* __restrict__ counts, int* __restrict__ rowptr,
                            int* __restrict__ cursor, float* __restrict__ scal) {
  __shared__ int sdata[1024];
  __shared__ int s_carry;
  __shared__ float wsum[16];
  int t = threadIdx.x;
  if (t == 0) s_carry = 0;
  __syncthreads();
  float logsum = 0.f;
  for (int base = 0; base < NN; base += 1024) {
    int i = base + t;
    int c = (i < NN) ? counts[i] : 0;
    if (i < NN) logsum += log1pf((float)c);
    sdata[t] = c;
    __syncthreads();
    for (int off = 1; off < 1024; off <<= 1) {
      int v = (t >= off) ? sdata[t - off] : 0;
      __syncthreads();
      sdata[t] += v;
      __syncthreads();
    }
    int incl = sdata[t];
    int tot = sdata[1023];
    int excl = incl - c;
    if (i < NN) { int r = s_carry + excl; rowptr[i] = r; cursor[i] = r; }
    __syncthreads();
    if (t == 0) s_carry += tot;
    __syncthreads();
  }
  if (t == 0) rowptr[NN] = s_carry;
  for (int off = 32; off > 0; off >>= 1) logsum += __shfl_down(logsum, off, 64);
  if ((t & 63) == 0) wsum[t >> 6] = logsum;
  __syncthreads();
  if (t == 0) {
    float s = 0.f;
    for (int i = 0; i < 16; i++) s += wsum[i];
    scal[0] = s / (float)NN;
  }
}

__global__ void degs_kernel(const int* __restrict__ counts, const float* __restrict__ scal,
                            float* __restrict__ amp, float* __restrict__ att) {
  int i = blockIdx.x * blockDim.x + threadIdx.x;
  if (i < NN) {
    float deg = fmaxf((float)counts[i], 1.f);
    float ld = logf(deg + 1.f);
    float al = scal[0];
    amp[i] = ld / al;
    att[i] = al / ld;
  }
}

__global__ void scatter_kernel(const int* __restrict__ src, const int* __restrict__ dst,
                               int* __restrict__ cursor, int* __restrict__ ssrc) {
  int e = blockIdx.x * blockDim.x + threadIdx.x;
  if (e < NE) {
    int p = atomicAdd(&cursor[dst[e]], 1);
    ssrc[p] = src[e];
  }
}

// ---------------------------------------------------------------- generic 64-wide GEMM
// C[M,64 slab] = A[M,K] @ W[K,64] (+bias). Tile 64 nodes x 64 cols, 256 threads.
// Natural [node][k] A-slab (float4 staging, broadcast reads) — same pattern as post_kernel.
__global__ __launch_bounds__(256, 4) void gemm64_kernel(
    const float* __restrict__ A, int lda, int K,
    const float* __restrict__ W, int ldw,
    const float* __restrict__ bias,
    float* __restrict__ C, int ldc) {
  __shared__ __align__(16) float As[64][36];  // 64 nodes x 32 k
  __shared__ __align__(16) float Ws[32][68];  // 32 k x 64 c
  int t = threadIdx.x;
  int n0 = blockIdx.x * 64;
  int nq = (t >> 4) * 4, cq = (t & 15) * 4;
  float acc[4][4] = {};
  for (int k0 = 0; k0 < K; k0 += 32) {
    // stage A slab: 64 nodes x 32 k = 512 float4, 2 per thread (8 lanes/node)
#pragma unroll
    for (int i = 0; i < 2; i++) {
      int fl = t + i * 256;
      int nl = fl >> 3, f4 = fl & 7;
      int row = n0 + nl; if (row >= NN) row = NN - 1;
      *(float4*)&As[nl][f4 * 4] = *(const float4*)&A[(size_t)row * lda + k0 + f4 * 4];
    }
    // stage W slab: 32 k x 64 c = 512 float4, 2 per thread
#pragma unroll
    for (int i = 0; i < 2; i++) {
      int fl = t + i * 256;
      int kl = fl >> 4, c4 = fl & 15;
      *(float4*)&Ws[kl][c4 * 4] = *(const float4*)&W[(size_t)(k0 + kl) * ldw + c4 * 4];
    }
    __syncthreads();
#pragma unroll
    for (int k = 0; k < 32; k++) {
      float4 w = *(const float4*)&Ws[k][cq];
      float wv[4] = {w.x, w.y, w.z, w.w};
      float av[4] = {As[nq + 0][k], As[nq + 1][k], As[nq + 2][k], As[nq + 3][k]};
#pragma unroll
      for (int i = 0; i < 4; i++)
#pragma unroll
        for (int j = 0; j < 4; j++) acc[i][j] += av[i] * wv[j];
    }
    __syncthreads();
  }
#pragma unroll
  for (int i = 0; i < 4; i++) {
    int n = n0 + nq + i;
    if (n < NN) {
      float4 o = make_float4(acc[i][0], acc[i][1], acc[i][2], acc[i][3]);
      if (bias) {
        float4 b4 = *(const float4*)&bias[cq];
        o.x += b4.x; o.y += b4.y; o.z += b4.z; o.w += b4.w;
      }
      *(float4*)&C[(size_t)n * ldc + cq] = o;
    }
  }
}

// ---------------------------------------------------------------- aggregation
// one wave per node: h_e = pd[n] + ps[src]; accumulate sum/sq/min/max
template <int F>
__global__ __launch_bounds__(256) void agg_kernel(
    const float* __restrict__ pd, const float* __restrict__ ps,
    const int* __restrict__ rowptr, const int* __restrict__ ssrc,
    float* __restrict__ agg) {
  constexpr int C = F / 64;
  int lane = threadIdx.x & 63;
  int wid = threadIdx.x >> 6;
  int n = blockIdx.x * 4 + wid;
  if (n >= NN) return;
  int beg = rowptr[n], end = rowptr[n + 1];
  float pdv[C], sum[C], sq[C], mn[C], mx[C];
#pragma unroll
  for (int c = 0; c < C; c++) {
    pdv[c] = pd[(size_t)n * F + lane + 64 * c];
    sum[c] = 0.f; sq[c] = 0.f; mn[c] = INFINITY; mx[c] = -INFINITY;
  }
  for (int e = beg; e < end; e++) {
    int s = ssrc[e];
#pragma unroll
    for (int c = 0; c < C; c++) {
      float h = pdv[c] + ps[(size_t)s * F + lane + 64 * c];
      sum[c] += h; sq[c] += h * h;
      mn[c] = fminf(mn[c], h); mx[c] = fmaxf(mx[c], h);
    }
  }
  int cnt = end - beg;
  float deg = fmaxf((float)cnt, 1.f);
  float inv = 1.f / deg;
#pragma unroll
  for (int c = 0; c < C; c++) {
    float mean = sum[c] * inv;
    float var = sq[c] * inv - mean * mean;
    float sd = sqrtf(fmaxf(var, 0.f) + 1e-5f);
    float mnv = cnt > 0 ? mn[c] : 0.f;
    float mxv = cnt > 0 ? mx[c] : 0.f;
    size_t b = (size_t)n * 4 * F + lane + 64 * c;
    agg[b] = mean;
    agg[b + F] = mnv;
    agg[b + 2 * F] = mxv;
    agg[b + 3 * F] = sd;
  }
}

// ---------------------------------------------------------------- post NN (fused)
// u = [h_in, agg, amp*agg, att*agg] @ pw + pb ; out = elu(u @ lw + lb + skip)
// Natural [node][k] LDS layouts (conflict-free writes, broadcast reads);
// slab-uniform region select; U aliased onto X/W slabs; 35.8 KB LDS, VGPR<=128.
template <int F>
__global__ __launch_bounds__(256, 4) void post_kernel(
    const float* __restrict__ h_in, const float* __restrict__ agg,
    const float* __restrict__ amp, const float* __restrict__ att,
    const float* __restrict__ pw, const float* __restrict__ pb,
    const float* __restrict__ lw, const float* __restrict__ lb,
    const float* __restrict__ skip, float* __restrict__ out) {
  // Xs: 64 nodes x 32 k slab, stride 36
  // Ws: 32 k x 64 cols, stride 68
  // Us (after K-loop) aliases Xs+Ws storage: 64 nodes x 64 cols, stride 68
  __shared__ __align__(16) char lds_pool[(64 * 36 + 32 * 68) * 4];  // 17920 B
  float (*Xs)[36] = (float(*)[36])lds_pool;
  float (*Ws)[68] = (float(*)[68])(lds_pool + 64 * 36 * 4);
  float (*Us)[68] = (float(*)[68])lds_pool;
  __shared__ __align__(16) float Lws[64][68];
  __shared__ float s_amp[64], s_att[64];

  int t = threadIdx.x;
  int n0 = blockIdx.x * 64;

  // stage lin_w (64x64) once, float4
  const float4* lw4 = (const float4*)lw;
#pragma unroll
  for (int i = 0; i < 4; i++) {
    int fl = t + i * 256;  // float4 index: row = fl>>4, col4 = fl&15
    *(float4*)&Lws[fl >> 4][(fl & 15) * 4] = lw4[fl];
  }
  if (t < 64) {
    int n = n0 + t; if (n >= NN) n = NN - 1;
    s_amp[t] = amp[n];
    s_att[t] = att[n];
  }
  __syncthreads();

  int nq = (t >> 4) * 4, cq = (t & 15) * 4;
  float acc[4][4] = {};
  const int KT = 13 * F;
  for (int k0 = 0; k0 < KT; k0 += 32) {
    // region select — uniform across the block for each 32-k slab
    const float* src; int ldx, koff, mode;
    if (k0 < F)          { src = h_in; ldx = F;     koff = k0;         mode = 0; }
    else if (k0 < 5 * F) { src = agg;  ldx = 4 * F; koff = k0 - F;     mode = 0; }
    else if (k0 < 9 * F) { src = agg;  ldx = 4 * F; koff = k0 - 5 * F; mode = 1; }
    else                 { src = agg;  ldx = 4 * F; koff = k0 - 9 * F; mode = 2; }
    // stage X slab: 64 nodes x 32 k = 512 float4, 2 per thread; lanes 8-per-node
#pragma unroll
    for (int i = 0; i < 2; i++) {
      int fl = t + i * 256;           // node = fl>>3, f4 = fl&7
      int nl = fl >> 3, f4 = fl & 7;
      int n = n0 + nl; if (n >= NN) n = NN - 1;
      float4 v = *(const float4*)&src[(size_t)n * ldx + koff + f4 * 4];
      float s = (mode == 0) ? 1.f : (mode == 1 ? s_amp[nl] : s_att[nl]);
      v.x *= s; v.y *= s; v.z *= s; v.w *= s;
      *(float4*)&Xs[nl][f4 * 4] = v;
    }
    // stage W slab: 32 k x 64 c = 512 float4, 2 per thread
    const float4* wp4 = (const float4*)(pw + (size_t)k0 * 64);
#pragma unroll
    for (int i = 0; i < 2; i++) {
      int fl = t + i * 256;           // kl = fl>>4, c4 = fl&15
      *(float4*)&Ws[fl >> 4][(fl & 15) * 4] = wp4[fl];
    }
    __syncthreads();
#pragma unroll
    for (int k = 0; k < 32; k++) {
      float4 w = *(const float4*)&Ws[k][cq];
      float wv[4] = {w.x, w.y, w.z, w.w};
      float av[4] = {Xs[nq + 0][k], Xs[nq + 1][k], Xs[nq + 2][k], Xs[nq + 3][k]};
#pragma unroll
      for (int i = 0; i < 4; i++)
#pragma unroll
        for (int j = 0; j < 4; j++) acc[i][j] += av[i] * wv[j];
    }
    __syncthreads();
  }

  // u = acc + pb -> Us [node][c] (aliases Xs/Ws; safe after the loop's last barrier)
  float4 pb4 = *(const float4*)&pb[cq];
#pragma unroll
  for (int i = 0; i < 4; i++) {
    float4 u = make_float4(acc[i][0] + pb4.x, acc[i][1] + pb4.y,
                           acc[i][2] + pb4.z, acc[i][3] + pb4.w);
    *(float4*)&Us[nq + i][cq] = u;
  }
  __syncthreads();

  float acc2[4][4] = {};
#pragma unroll
  for (int k = 0; k < 64; k++) {
    float4 w = *(const float4*)&Lws[k][cq];
    float wv[4] = {w.x, w.y, w.z, w.w};
    float av[4] = {Us[nq + 0][k], Us[nq + 1][k], Us[nq + 2][k], Us[nq + 3][k]};
#pragma unroll
    for (int i = 0; i < 4; i++)
#pragma unroll
      for (int j = 0; j < 4; j++) acc2[i][j] += av[i] * wv[j];
  }

  float4 lb4 = *(const float4*)&lb[cq];
#pragma unroll
  for (int i = 0; i < 4; i++) {
    int n = n0 + nq + i;
    if (n < NN) {
      float4 sk4 = *(const float4*)&skip[(size_t)n * 64 + cq];
      float v0 = acc2[i][0] + lb4.x + sk4.x;
      float v1 = acc2[i][1] + lb4.y + sk4.y;
      float v2 = acc2[i][2] + lb4.z + sk4.z;
      float v3 = acc2[i][3] + lb4.w + sk4.w;
      float4 o = make_float4(v0 > 0.f ? v0 : expm1f(v0),
                             v1 > 0.f ? v1 : expm1f(v1),
                             v2 > 0.f ? v2 : expm1f(v2),
                             v3 > 0.f ? v3 : expm1f(v3));
      *(float4*)&out[(size_t)n * 64 + cq] = o;
    }
  }
}

// ---------------------------------------------------------------- launch
extern "C" void kernel_launch(void* const* d_in, const int* in_sizes, int n_in,
                              void* d_out, int out_size, void* d_ws, size_t ws_size,
                              hipStream_t stream) {
  const float* x = (const float*)d_in[0];
  const int* ei = (const int*)d_in[1];
  const int* esrc = ei;
  const int* edst = ei + NE;
  const float* pre_w[3]  = {(const float*)d_in[2],  (const float*)d_in[8],  (const float*)d_in[14]};
  const float* pre_b[3]  = {(const float*)d_in[3],  (const float*)d_in[9],  (const float*)d_in[15]};
  const float* post_w[3] = {(const float*)d_in[4],  (const float*)d_in[10], (const float*)d_in[16]};
  const float* post_b[3] = {(const float*)d_in[5],  (const float*)d_in[11], (const float*)d_in[17]};
  const float* lin_w[3]  = {(const float*)d_in[6],  (const float*)d_in[12], (const float*)d_in[18]};
  const float* lin_b[3]  = {(const float*)d_in[7],  (const float*)d_in[13], (const float*)d_in[19]};
  const float* skip_w = (const float*)d_in[20];
  const float* skip_b = (const float*)d_in[21];

  char* p = (char*)d_ws;
  auto alloc = [&](size_t b) { char* r = p; p += (b + 255) & ~(size_t)255; return r; };
  int* counts  = (int*)alloc((size_t)NN * 4);
  int* rowptr  = (int*)alloc((size_t)(NN + 1) * 4);
  int* cursor  = (int*)alloc((size_t)NN * 4);
  int* ssrc    = (int*)alloc((size_t)NE * 4);
  float* amp   = (float*)alloc((size_t)NN * 4);
  float* att   = (float*)alloc((size_t)NN * 4);
  float* scal  = (float*)alloc(256);
  float* pd    = (float*)alloc((size_t)NN * 128 * 4);
  float* ps    = (float*)alloc((size_t)NN * 128 * 4);
  float* agg   = (float*)alloc((size_t)NN * 512 * 4);
  float* ha    = (float*)alloc((size_t)NN * 64 * 4);
  float* hb    = (float*)alloc((size_t)NN * 64 * 4);
  float* sk    = (float*)alloc((size_t)NN * 64 * 4);
  (void)ws_size; (void)in_sizes; (void)n_in; (void)out_size;

  zero_counts_kernel<<<(NN + 255) / 256, 256, 0, stream>>>(counts);
  count_kernel<<<(NE + 255) / 256, 256, 0, stream>>>(edst, counts);
  scan_kernel<<<1, 1024, 0, stream>>>(counts, rowptr, cursor, scal);
  degs_kernel<<<(NN + 255) / 256, 256, 0, stream>>>(counts, scal, amp, att);
  scatter_kernel<<<(NE + 255) / 256, 256, 0, stream>>>(esrc, edst, cursor, ssrc);

  int gn = (NN + 63) / 64;

  // skip = x @ skip_w + skip_b
  gemm64_kernel<<<gn, 256, 0, stream>>>(x, 128, 128, skip_w, 64, skip_b, sk, 64);

  // ---- layer 0 (F = 128)
  gemm64_kernel<<<gn, 256, 0, stream>>>(x, 128, 128, pre_w[0],           128, pre_b[0],      pd,      128);
  gemm64_kernel<<<gn, 256, 0, stream>>>(x, 128, 128, pre_w[0] + 64,      128, pre_b[0] + 64, pd + 64, 128);
  gemm64_kernel<<<gn, 256, 0, stream>>>(x, 128, 128, pre_w[0] + 128*128,      128, nullptr,  ps,      128);
  gemm64_kernel<<<gn, 256, 0, stream>>>(x, 128, 128, pre_w[0] + 128*128 + 64, 128, nullptr,  ps + 64, 128);
  agg_kernel<128><<<(NN + 3) / 4, 256, 0, stream>>>(pd, ps, rowptr, ssrc, agg);
  post_kernel<128><<<gn, 256, 0, stream>>>(x, agg, amp, att, post_w[0], post_b[0],
                                           lin_w[0], lin_b[0], sk, ha);

  // ---- layer 1 (F = 64)
  gemm64_kernel<<<gn, 256, 0, stream>>>(ha, 64, 64, pre_w[1],         64, pre_b[1], pd, 64);
  gemm64_kernel<<<gn, 256, 0, stream>>>(ha, 64, 64, pre_w[1] + 64*64, 64, nullptr,  ps, 64);
  agg_kernel<64><<<(NN + 3) / 4, 256, 0, stream>>>(pd, ps, rowptr, ssrc, agg);
  post_kernel<64><<<gn, 256, 0, stream>>>(ha, agg, amp, att, post_w[1], post_b[1],
                                          lin_w[1], lin_b[1], ha, hb);

  // ---- layer 2 (F = 64)
  gemm64_kernel<<<gn, 256, 0, stream>>>(hb, 64, 64, pre_w[2],         64, pre_b[2], pd, 64);
  gemm64_kernel<<<gn, 256, 0, stream>>>(hb, 64, 64, pre_w[2] + 64*64, 64, nullptr,  ps, 64);
  agg_kernel<64><<<(NN + 3) / 4, 256, 0, stream>>>(pd, ps, rowptr, ssrc, agg);
  post_kernel<64><<<gn, 256, 0, stream>>>(hb, agg, amp, att, post_w[2], post_b[2],
                                          lin_w[2], lin_b[2], hb, (float*)d_out);
}

// Round 14
// 2819.480 us; speedup vs baseline: 1.0265x; 1.0265x over previous
//
#include <hip/hip_runtime.h>
#include <math.h>

#define NN 50000
#define NE 800000

// ---------------------------------------------------------------- utility
__global__ void zero_counts_kernel(int* counts) {
  int i = blockIdx.x * blockDim.x + threadIdx.x;
  if (i < NN) counts[i] = 0;
}

__global__ void count_kernel(const int* __restrict__ dst, int* __restrict__ counts) {
  int e = blockIdx.x * blockDim.x + threadIdx.x;
  if (e < NE) atomicAdd(&counts[dst[e]], 1);
}

// single block, 1024 threads: exclusive scan of counts -> rowptr/cursor,
// plus avg_log = mean(log1p(counts)) -> scal[0]
__global__ void scan_kernel(const int* __restrict__ counts, int* __restrict__ rowptr,
                            int* __restrict__ cursor, float* __restrict__ scal) {
  __shared__ int sdata[1024];
  __shared__ int s_carry;
  __shared__ float wsum[16];
  int t = threadIdx.x;
  if (t == 0) s_carry = 0;
  __syncthreads();
  float logsum = 0.f;
  for (int base = 0; base < NN; base += 1024) {
    int i = base + t;
    int c = (i < NN) ? counts[i] : 0;
    if (i < NN) logsum += log1pf((float)c);
    sdata[t] = c;
    __syncthreads();
    for (int off = 1; off < 1024; off <<= 1) {
      int v = (t >= off) ? sdata[t - off] : 0;
      __syncthreads();
      sdata[t] += v;
      __syncthreads();
    }
    int incl = sdata[t];
    int tot = sdata[1023];
    int excl = incl - c;
    if (i < NN) { int r = s_carry + excl; rowptr[i] = r; cursor[i] = r; }
    __syncthreads();
    if (t == 0) s_carry += tot;
    __syncthreads();
  }
  if (t == 0) rowptr[NN] = s_carry;
  for (int off = 32; off > 0; off >>= 1) logsum += __shfl_down(logsum, off, 64);
  if ((t & 63) == 0) wsum[t >> 6] = logsum;
  __syncthreads();
  if (t == 0) {
    float s = 0.f;
    for (int i = 0; i < 16; i++) s += wsum[i];
    scal[0] = s / (float)NN;
  }
}

__global__ void degs_kernel(const int* __restrict__ counts, const float* __restrict__ scal,
                            float* __restrict__ amp, float* __restrict__ att) {
  int i = blockIdx.x * blockDim.x + threadIdx.x;
  if (i < NN) {
    float deg = fmaxf((float)counts[i], 1.f);
    float ld = logf(deg + 1.f);
    float al = scal[0];
    amp[i] = ld / al;
    att[i] = al / ld;
  }
}

__global__ void scatter_kernel(const int* __restrict__ src, const int* __restrict__ dst,
                               int* __restrict__ cursor, int* __restrict__ ssrc) {
  int e = blockIdx.x * blockDim.x + threadIdx.x;
  if (e < NE) {
    int p = atomicAdd(&cursor[dst[e]], 1);
    ssrc[p] = src[e];
  }
}

// ---------------------------------------------------------------- generic 64-wide GEMM (skip only)
__global__ __launch_bounds__(256, 4) void gemm64_kernel(
    const float* __restrict__ A, int lda, int K,
    const float* __restrict__ W, int ldw,
    const float* __restrict__ bias,
    float* __restrict__ C, int ldc) {
  __shared__ __align__(16) float As[64][36];  // 64 nodes x 32 k
  __shared__ __align__(16) float Ws[32][68];  // 32 k x 64 c
  int t = threadIdx.x;
  int n0 = blockIdx.x * 64;
  int nq = (t >> 4) * 4, cq = (t & 15) * 4;
  float acc[4][4] = {};
  for (int k0 = 0; k0 < K; k0 += 32) {
#pragma unroll
    for (int i = 0; i < 2; i++) {
      int fl = t + i * 256;
      int nl = fl >> 3, f4 = fl & 7;
      int row = n0 + nl; if (row >= NN) row = NN - 1;
      *(float4*)&As[nl][f4 * 4] = *(const float4*)&A[(size_t)row * lda + k0 + f4 * 4];
    }
#pragma unroll
    for (int i = 0; i < 2; i++) {
      int fl = t + i * 256;
      int kl = fl >> 4, c4 = fl & 15;
      *(float4*)&Ws[kl][c4 * 4] = *(const float4*)&W[(size_t)(k0 + kl) * ldw + c4 * 4];
    }
    __syncthreads();
#pragma unroll
    for (int k = 0; k < 32; k++) {
      float4 w = *(const float4*)&Ws[k][cq];
      float wv[4] = {w.x, w.y, w.z, w.w};
      float av[4] = {As[nq + 0][k], As[nq + 1][k], As[nq + 2][k], As[nq + 3][k]};
#pragma unroll
      for (int i = 0; i < 4; i++)
#pragma unroll
        for (int j = 0; j < 4; j++) acc[i][j] += av[i] * wv[j];
    }
    __syncthreads();
  }
#pragma unroll
  for (int i = 0; i < 4; i++) {
    int n = n0 + nq + i;
    if (n < NN) {
      float4 o = make_float4(acc[i][0], acc[i][1], acc[i][2], acc[i][3]);
      if (bias) {
        float4 b4 = *(const float4*)&bias[cq];
        o.x += b4.x; o.y += b4.y; o.z += b4.z; o.w += b4.w;
      }
      *(float4*)&C[(size_t)n * ldc + cq] = o;
    }
  }
}

// ---------------------------------------------------------------- dual-slab GEMM
// Reads A once, computes C1 = A@W1 (+b1) and C2 = A@W2 (+b2), each 64 cols.
// Tile: 64 nodes x 128 cols; thread = 4 nodes x 8 cols; (t&15)<8 -> C1 else C2.
__global__ __launch_bounds__(256, 4) void gemm_dual_kernel(
    const float* __restrict__ A, int lda, int K,
    const float* __restrict__ W1, const float* __restrict__ W2, int ldw,
    const float* __restrict__ b1, const float* __restrict__ b2,
    float* __restrict__ C1, int ldc1, float* __restrict__ C2, int ldc2) {
  __shared__ __align__(16) float As[64][36];   // 64 nodes x 32 k
  __shared__ __align__(16) float Ws[32][132];  // 32 k x (64 | 64) c
  int t = threadIdx.x;
  int n0 = blockIdx.x * 64;
  int nq = (t >> 4) * 4;          // 4 nodes
  int cq = (t & 15) * 8;          // 8 cols in [0,128)
  float acc[4][8] = {};
  for (int k0 = 0; k0 < K; k0 += 32) {
#pragma unroll
    for (int i = 0; i < 2; i++) {
      int fl = t + i * 256;
      int nl = fl >> 3, f4 = fl & 7;
      int row = n0 + nl; if (row >= NN) row = NN - 1;
      *(float4*)&As[nl][f4 * 4] = *(const float4*)&A[(size_t)row * lda + k0 + f4 * 4];
    }
#pragma unroll
    for (int i = 0; i < 2; i++) {
      int fl = t + i * 256;
      int kl = fl >> 4, c4 = (fl & 15) * 4;
      *(float4*)&Ws[kl][c4] = *(const float4*)&W1[(size_t)(k0 + kl) * ldw + c4];
    }
#pragma unroll
    for (int i = 0; i < 2; i++) {
      int fl = t + i * 256;
      int kl = fl >> 4, c4 = (fl & 15) * 4;
      *(float4*)&Ws[kl][64 + c4] = *(const float4*)&W2[(size_t)(k0 + kl) * ldw + c4];
    }
    __syncthreads();
#pragma unroll
    for (int k = 0; k < 32; k++) {
      float av[4] = {As[nq + 0][k], As[nq + 1][k], As[nq + 2][k], As[nq + 3][k]};
      float4 wl = *(const float4*)&Ws[k][cq];
      float4 wh = *(const float4*)&Ws[k][cq + 4];
      float wv[8] = {wl.x, wl.y, wl.z, wl.w, wh.x, wh.y, wh.z, wh.w};
#pragma unroll
      for (int i = 0; i < 4; i++)
#pragma unroll
        for (int j = 0; j < 8; j++) acc[i][j] += av[i] * wv[j];
    }
    __syncthreads();
  }
  bool hi = (t & 15) >= 8;
  float* Cd = hi ? C2 : C1;
  int ldc = hi ? ldc2 : ldc1;
  const float* bs = hi ? b2 : b1;
  int col = hi ? cq - 64 : cq;  // [0,64)
  float bv[8] = {};
  if (bs) {
    float4 blo = *(const float4*)&bs[col];
    float4 bhi = *(const float4*)&bs[col + 4];
    bv[0] = blo.x; bv[1] = blo.y; bv[2] = blo.z; bv[3] = blo.w;
    bv[4] = bhi.x; bv[5] = bhi.y; bv[6] = bhi.z; bv[7] = bhi.w;
  }
#pragma unroll
  for (int i = 0; i < 4; i++) {
    int n = n0 + nq + i;
    if (n < NN) {
      float4 lo = make_float4(acc[i][0] + bv[0], acc[i][1] + bv[1],
                              acc[i][2] + bv[2], acc[i][3] + bv[3]);
      float4 hi4 = make_float4(acc[i][4] + bv[4], acc[i][5] + bv[5],
                               acc[i][6] + bv[6], acc[i][7] + bv[7]);
      *(float4*)&Cd[(size_t)n * ldc + col] = lo;
      *(float4*)&Cd[(size_t)n * ldc + col + 4] = hi4;
    }
  }
}

// ---------------------------------------------------------------- aggregation
// one wave per node: h_e = pd[n] + ps[src]; accumulate sum/sq/min/max
template <int F>
__global__ __launch_bounds__(256) void agg_kernel(
    const float* __restrict__ pd, const float* __restrict__ ps,
    const int* __restrict__ rowptr, const int* __restrict__ ssrc,
    float* __restrict__ agg) {
  constexpr int C = F / 64;
  int lane = threadIdx.x & 63;
  int wid = threadIdx.x >> 6;
  int n = blockIdx.x * 4 + wid;
  if (n >= NN) return;
  int beg = rowptr[n], end = rowptr[n + 1];
  float pdv[C], sum[C], sq[C], mn[C], mx[C];
#pragma unroll
  for (int c = 0; c < C; c++) {
    pdv[c] = pd[(size_t)n * F + lane + 64 * c];
    sum[c] = 0.f; sq[c] = 0.f; mn[c] = INFINITY; mx[c] = -INFINITY;
  }
  for (int e = beg; e < end; e++) {
    int s = ssrc[e];
#pragma unroll
    for (int c = 0; c < C; c++) {
      float h = pdv[c] + ps[(size_t)s * F + lane + 64 * c];
      sum[c] += h; sq[c] += h * h;
      mn[c] = fminf(mn[c], h); mx[c] = fmaxf(mx[c], h);
    }
  }
  int cnt = end - beg;
  float deg = fmaxf((float)cnt, 1.f);
  float inv = 1.f / deg;
#pragma unroll
  for (int c = 0; c < C; c++) {
    float mean = sum[c] * inv;
    float var = sq[c] * inv - mean * mean;
    float sd = sqrtf(fmaxf(var, 0.f) + 1e-5f);
    float mnv = cnt > 0 ? mn[c] : 0.f;
    float mxv = cnt > 0 ? mx[c] : 0.f;
    size_t b = (size_t)n * 4 * F + lane + 64 * c;
    agg[b] = mean;
    agg[b + F] = mnv;
    agg[b + 2 * F] = mxv;
    agg[b + 3 * F] = sd;
  }
}

// ---------------------------------------------------------------- post NN (fused)
// Scaler folding: u = h@W0 + agg@WA + amp*(agg@WB) + att*(agg@WC) + pb,
// since amp/att are per-node scalars. agg is read ONCE (was 3x).
// Then out = elu(u @ lw + lb + skip).
template <int F>
__global__ __launch_bounds__(256, 4) void post_kernel(
    const float* __restrict__ h_in, const float* __restrict__ agg,
    const float* __restrict__ amp, const float* __restrict__ att,
    const float* __restrict__ pw, const float* __restrict__ pb,
    const float* __restrict__ lw, const float* __restrict__ lb,
    const float* __restrict__ skip, float* __restrict__ out) {
  // Pool (floats): phase A: Xs[64][36] @0 | WA[32][68] @2304 | WB @4480 | WC @6656
  //                phase B: Us[64][68] @0 (4352<=4480 ok) | Lws[64][68] @4480
  __shared__ __align__(16) float pool[64 * 36 + 3 * 32 * 68];  // 8832 floats = 35328 B
  float (*Xs)[36] = (float(*)[36])pool;
  float (*WAs)[68] = (float(*)[68])(pool + 64 * 36);
  float (*WBs)[68] = (float(*)[68])(pool + 64 * 36 + 32 * 68);
  float (*WCs)[68] = (float(*)[68])(pool + 64 * 36 + 2 * 32 * 68);
  float (*Us)[68] = (float(*)[68])pool;
  float (*Lws)[68] = (float(*)[68])(pool + 64 * 36 + 32 * 68);
  __shared__ float s_amp[64], s_att[64];

  int t = threadIdx.x;
  int n0 = blockIdx.x * 64;
  if (t < 64) {
    int n = n0 + t; if (n >= NN) n = NN - 1;
    s_amp[t] = amp[n];
    s_att[t] = att[n];
  }

  int nq = (t >> 4) * 4, cq = (t & 15) * 4;
  float accA[4][4] = {}, accB[4][4] = {}, accC[4][4] = {};

  // ---- phase 1: h_in @ pw[0:F]  (accA only)
  for (int k0 = 0; k0 < F; k0 += 32) {
#pragma unroll
    for (int i = 0; i < 2; i++) {
      int fl = t + i * 256;
      int nl = fl >> 3, f4 = fl & 7;
      int n = n0 + nl; if (n >= NN) n = NN - 1;
      *(float4*)&Xs[nl][f4 * 4] = *(const float4*)&h_in[(size_t)n * F + k0 + f4 * 4];
    }
    const float4* wa4 = (const float4*)(pw + (size_t)k0 * 64);
#pragma unroll
    for (int i = 0; i < 2; i++) {
      int fl = t + i * 256;
      *(float4*)&WAs[fl >> 4][(fl & 15) * 4] = wa4[fl];
    }
    __syncthreads();
#pragma unroll
    for (int k = 0; k < 32; k++) {
      float4 w = *(const float4*)&WAs[k][cq];
      float wv[4] = {w.x, w.y, w.z, w.w};
      float av[4] = {Xs[nq + 0][k], Xs[nq + 1][k], Xs[nq + 2][k], Xs[nq + 3][k]};
#pragma unroll
      for (int i = 0; i < 4; i++)
#pragma unroll
        for (int j = 0; j < 4; j++) accA[i][j] += av[i] * wv[j];
    }
    __syncthreads();
  }

  // ---- phase 2: agg @ {WA=pw[F:5F], WB=pw[5F:9F], WC=pw[9F:13F]} — agg read once
  for (int k0 = 0; k0 < 4 * F; k0 += 32) {
#pragma unroll
    for (int i = 0; i < 2; i++) {
      int fl = t + i * 256;
      int nl = fl >> 3, f4 = fl & 7;
      int n = n0 + nl; if (n >= NN) n = NN - 1;
      *(float4*)&Xs[nl][f4 * 4] = *(const float4*)&agg[(size_t)n * 4 * F + k0 + f4 * 4];
    }
    const float4* wa4 = (const float4*)(pw + (size_t)(F + k0) * 64);
    const float4* wb4 = (const float4*)(pw + (size_t)(5 * F + k0) * 64);
    const float4* wc4 = (const float4*)(pw + (size_t)(9 * F + k0) * 64);
#pragma unroll
    for (int i = 0; i < 2; i++) {
      int fl = t + i * 256;
      int kl = fl >> 4, c16 = (fl & 15) * 4;
      *(float4*)&WAs[kl][c16] = wa4[fl];
      *(float4*)&WBs[kl][c16] = wb4[fl];
      *(float4*)&WCs[kl][c16] = wc4[fl];
    }
    __syncthreads();
#pragma unroll
    for (int k = 0; k < 32; k++) {
      float av[4] = {Xs[nq + 0][k], Xs[nq + 1][k], Xs[nq + 2][k], Xs[nq + 3][k]};
      float4 wa = *(const float4*)&WAs[k][cq];
      float4 wb = *(const float4*)&WBs[k][cq];
      float4 wc = *(const float4*)&WCs[k][cq];
      float wav[4] = {wa.x, wa.y, wa.z, wa.w};
      float wbv[4] = {wb.x, wb.y, wb.z, wb.w};
      float wcv[4] = {wc.x, wc.y, wc.z, wc.w};
#pragma unroll
      for (int i = 0; i < 4; i++)
#pragma unroll
        for (int j = 0; j < 4; j++) {
          accA[i][j] += av[i] * wav[j];
          accB[i][j] += av[i] * wbv[j];
          accC[i][j] += av[i] * wcv[j];
        }
    }
    __syncthreads();
  }

  // ---- u = accA + amp*accB + att*accC + pb -> Us; stage Lws (aliases WB/WC)
  float4 pb4 = *(const float4*)&pb[cq];
#pragma unroll
  for (int i = 0; i < 4; i++) {
    float a_ = s_amp[nq + i], t_ = s_att[nq + i];
    float4 u = make_float4(accA[i][0] + a_ * accB[i][0] + t_ * accC[i][0] + pb4.x,
                           accA[i][1] + a_ * accB[i][1] + t_ * accC[i][1] + pb4.y,
                           accA[i][2] + a_ * accB[i][2] + t_ * accC[i][2] + pb4.z,
                           accA[i][3] + a_ * accB[i][3] + t_ * accC[i][3] + pb4.w);
    *(float4*)&Us[nq + i][cq] = u;
  }
  const float4* lw4 = (const float4*)lw;
#pragma unroll
  for (int i = 0; i < 4; i++) {
    int fl = t + i * 256;
    *(float4*)&Lws[fl >> 4][(fl & 15) * 4] = lw4[fl];
  }
  __syncthreads();

  float acc2[4][4] = {};
#pragma unroll
  for (int k = 0; k < 64; k++) {
    float4 w = *(const float4*)&Lws[k][cq];
    float wv[4] = {w.x, w.y, w.z, w.w};
    float av[4] = {Us[nq + 0][k], Us[nq + 1][k], Us[nq + 2][k], Us[nq + 3][k]};
#pragma unroll
    for (int i = 0; i < 4; i++)
#pragma unroll
      for (int j = 0; j < 4; j++) acc2[i][j] += av[i] * wv[j];
  }

  float4 lb4 = *(const float4*)&lb[cq];
#pragma unroll
  for (int i = 0; i < 4; i++) {
    int n = n0 + nq + i;
    if (n < NN) {
      float4 sk4 = *(const float4*)&skip[(size_t)n * 64 + cq];
      float v0 = acc2[i][0] + lb4.x + sk4.x;
      float v1 = acc2[i][1] + lb4.y + sk4.y;
      float v2 = acc2[i][2] + lb4.z + sk4.z;
      float v3 = acc2[i][3] + lb4.w + sk4.w;
      float4 o = make_float4(v0 > 0.f ? v0 : expm1f(v0),
                             v1 > 0.f ? v1 : expm1f(v1),
                             v2 > 0.f ? v2 : expm1f(v2),
                             v3 > 0.f ? v3 : expm1f(v3));
      *(float4*)&out[(size_t)n * 64 + cq] = o;
    }
  }
}

// ---------------------------------------------------------------- launch
extern "C" void kernel_launch(void* const* d_in, const int* in_sizes, int n_in,
                              void* d_out, int out_size, void* d_ws, size_t ws_size,
                              hipStream_t stream) {
  const float* x = (const float*)d_in[0];
  const int* ei = (const int*)d_in[1];
  const int* esrc = ei;
  const int* edst = ei + NE;
  const float* pre_w[3]  = {(const float*)d_in[2],  (const float*)d_in[8],  (const float*)d_in[14]};
  const float* pre_b[3]  = {(const float*)d_in[3],  (const float*)d_in[9],  (const float*)d_in[15]};
  const float* post_w[3] = {(const float*)d_in[4],  (const float*)d_in[10], (const float*)d_in[16]};
  const float* post_b[3] = {(const float*)d_in[5],  (const float*)d_in[11], (const float*)d_in[17]};
  const float* lin_w[3]  = {(const float*)d_in[6],  (const float*)d_in[12], (const float*)d_in[18]};
  const float* lin_b[3]  = {(const float*)d_in[7],  (const float*)d_in[13], (const float*)d_in[19]};
  const float* skip_w = (const float*)d_in[20];
  const float* skip_b = (const float*)d_in[21];

  char* p = (char*)d_ws;
  auto alloc = [&](size_t b) { char* r = p; p += (b + 255) & ~(size_t)255; return r; };
  int* counts  = (int*)alloc((size_t)NN * 4);
  int* rowptr  = (int*)alloc((size_t)(NN + 1) * 4);
  int* cursor  = (int*)alloc((size_t)NN * 4);
  int* ssrc    = (int*)alloc((size_t)NE * 4);
  float* amp   = (float*)alloc((size_t)NN * 4);
  float* att   = (float*)alloc((size_t)NN * 4);
  float* scal  = (float*)alloc(256);
  float* pd    = (float*)alloc((size_t)NN * 128 * 4);
  float* ps    = (float*)alloc((size_t)NN * 128 * 4);
  float* agg   = (float*)alloc((size_t)NN * 512 * 4);
  float* ha    = (float*)alloc((size_t)NN * 64 * 4);
  float* hb    = (float*)alloc((size_t)NN * 64 * 4);
  float* sk    = (float*)alloc((size_t)NN * 64 * 4);
  (void)ws_size; (void)in_sizes; (void)n_in; (void)out_size;

  zero_counts_kernel<<<(NN + 255) / 256, 256, 0, stream>>>(counts);
  count_kernel<<<(NE + 255) / 256, 256, 0, stream>>>(edst, counts);
  scan_kernel<<<1, 1024, 0, stream>>>(counts, rowptr, cursor, scal);
  degs_kernel<<<(NN + 255) / 256, 256, 0, stream>>>(counts, scal, amp, att);
  scatter_kernel<<<(NE + 255) / 256, 256, 0, stream>>>(esrc, edst, cursor, ssrc);

  int gn = (NN + 63) / 64;

  // skip = x @ skip_w + skip_b
  gemm64_kernel<<<gn, 256, 0, stream>>>(x, 128, 128, skip_w, 64, skip_b, sk, 64);

  // ---- layer 0 (F = 128): pd = x@pw_top (+pb), ps = x@pw_bot — dual 64-col slabs
  gemm_dual_kernel<<<gn, 256, 0, stream>>>(x, 128, 128,
      pre_w[0], pre_w[0] + 64, 128, pre_b[0], pre_b[0] + 64, pd, 128, pd + 64, 128);
  gemm_dual_kernel<<<gn, 256, 0, stream>>>(x, 128, 128,
      pre_w[0] + 128 * 128, pre_w[0] + 128 * 128 + 64, 128, nullptr, nullptr,
      ps, 128, ps + 64, 128);
  agg_kernel<128><<<(NN + 3) / 4, 256, 0, stream>>>(pd, ps, rowptr, ssrc, agg);
  post_kernel<128><<<gn, 256, 0, stream>>>(x, agg, amp, att, post_w[0], post_b[0],
                                           lin_w[0], lin_b[0], sk, ha);

  // ---- layer 1 (F = 64): pd = ha@W_top (+b), ps = ha@W_bot — one dual call
  gemm_dual_kernel<<<gn, 256, 0, stream>>>(ha, 64, 64,
      pre_w[1], pre_w[1] + 64 * 64, 64, pre_b[1], nullptr, pd, 64, ps, 64);
  agg_kernel<64><<<(NN + 3) / 4, 256, 0, stream>>>(pd, ps, rowptr, ssrc, agg);
  post_kernel<64><<<gn, 256, 0, stream>>>(ha, agg, amp, att, post_w[1], post_b[1],
                                          lin_w[1], lin_b[1], ha, hb);

  // ---- layer 2 (F = 64)
  gemm_dual_kernel<<<gn, 256, 0, stream>>>(hb, 64, 64,
      pre_w[2], pre_w[2] + 64 * 64, 64, pre_b[2], nullptr, pd, 64, ps, 64);
  agg_kernel<64><<<(NN + 3) / 4, 256, 0, stream>>>(pd, ps, rowptr, ssrc, agg);
  post_kernel<64><<<gn, 256, 0, stream>>>(hb, agg, amp, att, post_w[2], post_b[2],
                                          lin_w[2], lin_b[2], hb, (float*)d_out);
}